// Round 4
// baseline (204.393 us; speedup 1.0000x reference)
//
#include <hip/hip_runtime.h>
#include <hip/hip_bf16.h>
#include <stdint.h>

typedef __bf16 bf16_t;
typedef __bf16 bf16x8 __attribute__((ext_vector_type(8)));
typedef __bf16 bf16x4 __attribute__((ext_vector_type(4)));
typedef float f32x4 __attribute__((ext_vector_type(4)));
typedef float f32x16 __attribute__((ext_vector_type(16)));
typedef uint32_t u32x4 __attribute__((ext_vector_type(4)));

#define XN 2097152   // x elements (2*1024*1024)
#define WN 1048576   // each weight (1024*1024)

typedef __attribute__((address_space(1))) const uint8_t* gas_ptr;
typedef __attribute__((address_space(3))) uint8_t* las_ptr;

static __device__ __forceinline__ uint16_t bfbits(float f) {
    bf16_t b = (bf16_t)f;
    return __builtin_bit_cast(uint16_t, b);
}

// ---- cast f32 -> bf16 (linear part): x, vq_w, vk_w, vv_w, wo_w -> contiguous dst
__global__ void cast_k(const float* __restrict__ x,
    const float* __restrict__ a0, const float* __restrict__ a1,
    const float* __restrict__ a2, const float* __restrict__ a3,
    bf16_t* __restrict__ dst)
{
    const int TOTC = (XN + 4 * WN) / 4;
    for (int c = blockIdx.x * blockDim.x + threadIdx.x; c < TOTC; c += gridDim.x * blockDim.x) {
        int el = c * 4;
        const float* s;
        if (el < XN) {
            s = x + el;
        } else {
            int r = el - XN;
            int wi = r >> 20;
            int off = r & (WN - 1);
            const float* wp = (wi == 0) ? a0 : (wi == 1) ? a1 : (wi == 2) ? a2 : a3;
            s = wp + off;
        }
        float4 f = *(const float4*)s;
        bf16x4 o = { (bf16_t)f.x, (bf16_t)f.y, (bf16_t)f.z, (bf16_t)f.w };
        *(bf16x4*)(dst + el) = o;
    }
}

// ---- transpose f32 (1024x1024) -> bf16 transposed, per 128x128 tile, XOR-swizzled LDS
__global__ __launch_bounds__(256)
void trans_k(const float* __restrict__ s0, const float* __restrict__ s1,
             const float* __restrict__ s2, bf16_t* __restrict__ dstBase)
{
    const int gid = blockIdx.x;          // 192 blocks: 3 weights x 64 tiles
    const int w = gid >> 6, t6 = gid & 63;
    const int r0 = (t6 >> 3) * 128, c0 = (t6 & 7) * 128;
    const float* src = (w == 0) ? s0 : (w == 1) ? s1 : s2;
    bf16_t* dst = dstBase + (size_t)w * WN;

    __shared__ uint8_t tt[32768];        // [128 c][16 groups][16B], group ^= (c&15)
    const int t = threadIdx.x;

#pragma unroll
    for (int i = 0; i < 4; ++i) {
        const int lid = i * 256 + t;
        const int r4 = lid >> 5, c4 = lid & 31;
        const float* p = src + (size_t)(r0 + r4 * 4) * 1024 + c0 + c4 * 4;
        float4 a = *(const float4*)p;
        float4 b = *(const float4*)(p + 1024);
        float4 cv = *(const float4*)(p + 2048);
        float4 d = *(const float4*)(p + 3072);
        const float* af = (const float*)&a; const float* bf = (const float*)&b;
        const float* cf = (const float*)&cv; const float* df = (const float*)&d;
#pragma unroll
        for (int j = 0; j < 4; ++j) {
            const int cc = c4 * 4 + j;
            const int g = r4 >> 1, h = r4 & 1;
            bf16x4 o = { (bf16_t)af[j], (bf16_t)bf[j], (bf16_t)cf[j], (bf16_t)df[j] };
            *(bf16x4*)(tt + cc * 256 + ((g ^ (cc & 15)) << 4) + h * 8) = o;
        }
    }
    __syncthreads();
#pragma unroll
    for (int j = 0; j < 8; ++j) {
        const int lid = j * 256 + t;
        const int cc = lid >> 4, g = lid & 15;
        bf16x8 v = *(const bf16x8*)(tt + cc * 256 + ((g ^ (cc & 15)) << 4));
        *(bf16x8*)(dst + (size_t)(c0 + cc) * 1024 + r0 + g * 8) = v;
    }
}

// ---- combined bias: bqc[z][o] = dot(Vz[o,:], b_in_z) + b_out_z[o]
__global__ __launch_bounds__(256)
void biasc_k(const bf16_t* __restrict__ vbase,   // vq,vk,vv bf16, each WN
             const float* __restrict__ bi0, const float* __restrict__ bi1, const float* __restrict__ bi2,
             const float* __restrict__ bo0, const float* __restrict__ bo1, const float* __restrict__ bo2,
             float* __restrict__ out)
{
    const int bid = blockIdx.x;          // 768 = 3 x 256
    const int z = bid >> 8;
    const int wave = threadIdx.x >> 6, lane = threadIdx.x & 63;
    const int o = (bid & 255) * 4 + wave;
    const float* bi = (z == 0) ? bi0 : (z == 1) ? bi1 : bi2;
    const float* bo = (z == 0) ? bo0 : (z == 1) ? bo1 : bo2;
    const bf16_t* row = vbase + (size_t)z * WN + (size_t)o * 1024;

    float sum = 0.f;
#pragma unroll
    for (int i = 0; i < 2; ++i) {
        const int j = (lane + 64 * i) * 8;
        bf16x8 v = *(const bf16x8*)(row + j);
        float4 f0 = *(const float4*)(bi + j);
        float4 f1 = *(const float4*)(bi + j + 4);
        sum += (float)v[0] * f0.x + (float)v[1] * f0.y + (float)v[2] * f0.z + (float)v[3] * f0.w;
        sum += (float)v[4] * f1.x + (float)v[5] * f1.y + (float)v[6] * f1.z + (float)v[7] * f1.w;
    }
#pragma unroll
    for (int off = 1; off < 64; off <<= 1) sum += __shfl_xor(sum, off, 64);
    if (lane == 0) out[z * 1024 + o] = sum + bo[o];
}

// ---- MFMA GEMM: C = A @ W^T (+ bias). BM=128 fixed, BN in {64,128}.
// EPI 0: bf16 natural (combine). EPI 1: z0 scaled-natural / z1 K-frag / z2 V-frag.
// EPI 2: f32 natural.
#define QSCALE 0.36067376022224085f   // 0.25 * log2(e)

template<int EPI, int BN, bool HASBIAS, int MT, int NT, int NZ>
__global__ __launch_bounds__(256)
void gemm_k(const bf16_t* __restrict__ A0, const bf16_t* __restrict__ A1, const bf16_t* __restrict__ A2,
            const bf16_t* __restrict__ W0, const bf16_t* __restrict__ W1, const bf16_t* __restrict__ W2,
            const float* __restrict__ bias0, const float* __restrict__ bias1, const float* __restrict__ bias2,
            void* O0, void* O1, void* O2)
{
    constexpr int NACC = BN / 32;
    constexpr int TOT = MT * NT * NZ;
    const int bid = blockIdx.x;
    const int swz = (bid & 7) * (TOT / 8) + (bid >> 3);   // XCD-bijective
    const int z = (NZ == 1) ? 0 : swz / (MT * NT);
    const int rr = swz % (MT * NT);
    const int mt = rr / NT, nt = rr % NT;

    const bf16_t* A = (z == 0) ? A0 : (z == 1) ? A1 : A2;
    const bf16_t* W = (z == 0) ? W0 : (z == 1) ? W1 : W2;
    const float* bias = (z == 0) ? bias0 : (z == 1) ? bias1 : bias2;
    void* Ov = (z == 0) ? O0 : (z == 1) ? O1 : O2;

    __shared__ bf16_t As[128 * 64];
    __shared__ bf16_t Bs[BN * 64];

    const int tid = threadIdx.x;
    const int lane = tid & 63, wave = tid >> 6;
    const int lo = lane & 15, hi = lane >> 4;
    const int wr = wave >> 1, wc = wave & 1;
    const int m0 = mt * 128, n0 = nt * BN;

    f32x4 acc[4][NACC] = {};

    for (int kt = 0; kt < 16; ++kt) {
        const int K0 = kt * 64;
        __syncthreads();
#pragma unroll
        for (int i = 0; i < 4; ++i) {
            const int cbase = i * 256 + wave * 64;
            const int c = cbase + lane;
            const int row = c >> 3, ko = c & 7;
            const bf16_t* ga = A + (size_t)(m0 + row) * 1024 + K0 + ko * 8;
            __builtin_amdgcn_global_load_lds((gas_ptr)ga, (las_ptr)(As + cbase * 8), 16, 0, 0);
        }
#pragma unroll
        for (int i = 0; i < NACC; ++i) {
            const int cbase = i * 256 + wave * 64;
            const int c = cbase + lane;
            const int row = c >> 3, ko = c & 7;
            const bf16_t* gb = W + (size_t)(n0 + row) * 1024 + K0 + ko * 8;
            __builtin_amdgcn_global_load_lds((gas_ptr)gb, (las_ptr)(Bs + cbase * 8), 16, 0, 0);
        }
        __syncthreads();
#pragma unroll
        for (int kk = 0; kk < 2; ++kk) {
            const int kb = kk * 32 + hi * 8;
            bf16x8 af[4], bfr[NACC];
#pragma unroll
            for (int m = 0; m < 4; ++m) af[m] = *(const bf16x8*)&As[(wr * 64 + m * 16 + lo) * 64 + kb];
#pragma unroll
            for (int n = 0; n < NACC; ++n) bfr[n] = *(const bf16x8*)&Bs[(wc * (BN / 2) + n * 16 + lo) * 64 + kb];
#pragma unroll
            for (int m = 0; m < 4; ++m)
#pragma unroll
                for (int n = 0; n < NACC; ++n)
                    acc[m][n] = __builtin_amdgcn_mfma_f32_16x16x32_bf16(af[m], bfr[n], acc[m][n], 0, 0, 0);
        }
    }

#pragma unroll
    for (int n = 0; n < NACC; ++n) {
        const int col = n0 + wc * (BN / 2) + n * 16 + lo;
        const float bv = HASBIAS ? bias[col] : 0.f;
#pragma unroll
        for (int m = 0; m < 4; ++m) {
            const int r0 = m0 + wr * 64 + m * 16 + hi * 4;
            if (EPI == 2) {
                float* O = (float*)Ov;
#pragma unroll
                for (int r = 0; r < 4; ++r)
                    O[(size_t)(r0 + r) * 1024 + col] = acc[m][n][r] + bv;
            } else if (EPI == 0 || z == 0) {
                bf16_t* O = (bf16_t*)Ov;
                const float sc = (EPI == 1) ? QSCALE : 1.0f;
#pragma unroll
                for (int r = 0; r < 4; ++r)
                    O[(size_t)(r0 + r) * 1024 + col] = (bf16_t)((acc[m][n][r] + bv) * sc);
            } else if (z == 1) {
                // K fragment-order: chunk C = (s>>5)*64 + (h>>3)*32 + (s&31), elem C*8 + (h&7)
                bf16_t* O = (bf16_t*)Ov;
                const int cch = col >> 4, h = col & 15;
                const int bb = r0 >> 10;
                const size_t sb = (size_t)(cch * 2 + bb) * 16384;
#pragma unroll
                for (int r = 0; r < 4; ++r) {
                    const int ss = (r0 + r) & 1023;
                    const int C = ((ss >> 5) << 6) + ((h >> 3) << 5) + (ss & 31);
                    O[sb + C * 8 + (h & 7)] = (bf16_t)(acc[m][n][r] + bv);
                }
            } else {
                // V fragment-order: C = (s>>5)*64 + ((s>>4)&1)*32 + ((s>>3)&1)*16 + h, elem C*8 + (s&7)
                bf16_t* O = (bf16_t*)Ov;
                const int cch = col >> 4, h = col & 15;
                const int bb = r0 >> 10;
                const int s0 = r0 & 1023;
                const int C = ((s0 >> 5) << 6) + (((s0 >> 4) & 1) << 5) + (((s0 >> 3) & 1) << 4) + h;
                bf16x4 pv = { (bf16_t)(acc[m][n][0] + bv), (bf16_t)(acc[m][n][1] + bv),
                              (bf16_t)(acc[m][n][2] + bv), (bf16_t)(acc[m][n][3] + bv) };
                *(bf16x4*)(O + (size_t)(cch * 2 + bb) * 16384 + C * 8 + (s0 & 7)) = pv;
            }
        }
    }
}

// ---- attention: per (c,b), K/V staged in LDS fragment-order (unchanged from R2)
__global__ __launch_bounds__(512)
void attn_k(const bf16_t* __restrict__ qg, const bf16_t* __restrict__ kfr,
            const bf16_t* __restrict__ vfr, bf16_t* __restrict__ y)
{
    __shared__ bf16_t lds[32768];

    const int c = blockIdx.y, b = blockIdx.z;
    const int tid = threadIdx.x;
    const int lane = tid & 63, wave = tid >> 6;
    const int l31 = lane & 31, hi = lane >> 5;
    const int s = blockIdx.x * 256 + wave * 32 + l31;

    const bf16_t* kb = kfr + (size_t)(c * 2 + b) * 16384;
    const bf16_t* vb = vfr + (size_t)(c * 2 + b) * 16384;
#pragma unroll
    for (int i = 0; i < 4; ++i) {
        const int cbase = i * 512 + wave * 64;
        __builtin_amdgcn_global_load_lds((gas_ptr)(kb + (cbase + lane) * 8),
                                         (las_ptr)((uint8_t*)lds + cbase * 16), 16, 0, 0);
        __builtin_amdgcn_global_load_lds((gas_ptr)(vb + (cbase + lane) * 8),
                                         (las_ptr)((uint8_t*)lds + 32768 + cbase * 16), 16, 0, 0);
    }

    bf16x8 qf = *(const bf16x8*)(qg + ((size_t)(b * 1024 + s)) * 1024 + c * 16 + hi * 8);

    __syncthreads();

    f32x16 oacc = {};
    const f32x16 z16 = {};
    float den = 0.f;
    const int vslot = ((lane >> 5) * 16 + (lane & 15)) * 8;

    for (int jt = 0; jt < 32; ++jt) {
        bf16x8 kf  = *(const bf16x8*)&lds[jt * 512 + lane * 8];
        bf16x8 vf0 = *(const bf16x8*)&lds[16384 + jt * 512 + vslot];
        bf16x8 vf1 = *(const bf16x8*)&lds[16384 + jt * 512 + 256 + vslot];

        f32x16 st = __builtin_amdgcn_mfma_f32_32x32x16_bf16(kf, qf, z16, 0, 0, 0);

        float p[16];
#pragma unroll
        for (int r = 0; r < 16; ++r) { p[r] = __builtin_amdgcn_exp2f(st[r]); den += p[r]; }

        uint32_t pk[8];
#pragma unroll
        for (int w = 0; w < 8; ++w)
            pk[w] = (uint32_t)bfbits(p[2 * w]) | ((uint32_t)bfbits(p[2 * w + 1]) << 16);

        asm("v_permlane32_swap_b32 %0, %1" : "+v"(pk[0]), "+v"(pk[2]));
        asm("v_permlane32_swap_b32 %0, %1" : "+v"(pk[1]), "+v"(pk[3]));
        asm("v_permlane32_swap_b32 %0, %1" : "+v"(pk[4]), "+v"(pk[6]));
        asm("v_permlane32_swap_b32 %0, %1" : "+v"(pk[5]), "+v"(pk[7]));

        u32x4 f0v = { pk[0], pk[1], pk[2], pk[3] };
        u32x4 f1v = { pk[4], pk[5], pk[6], pk[7] };
        bf16x8 pf0 = __builtin_bit_cast(bf16x8, f0v);
        bf16x8 pf1 = __builtin_bit_cast(bf16x8, f1v);

        oacc = __builtin_amdgcn_mfma_f32_32x32x16_bf16(vf0, pf0, oacc, 0, 0, 0);
        oacc = __builtin_amdgcn_mfma_f32_32x32x16_bf16(vf1, pf1, oacc, 0, 0, 0);
    }

    float dtot = den + __shfl_xor(den, 32, 64);
    float rinv = 1.0f / dtot;

    const int bo = (c >> 1) & 1;
    const int so = (c & 1) * 512 + b * 256 + (s >> 2);
    const int f0i = (c >> 2) * 64 + (s & 3) * 16;
    bf16_t* yb = y + ((size_t)bo * 1024 + so) * 1024 + f0i + 4 * hi;
    bf16x4 o1 = { (bf16_t)(oacc[0] * rinv), (bf16_t)(oacc[1] * rinv),
                  (bf16_t)(oacc[2] * rinv), (bf16_t)(oacc[3] * rinv) };
    *(bf16x4*)(yb) = o1;
    bf16x4 o2 = { (bf16_t)(oacc[4] * rinv), (bf16_t)(oacc[5] * rinv),
                  (bf16_t)(oacc[6] * rinv), (bf16_t)(oacc[7] * rinv) };
    *(bf16x4*)(yb + 8) = o2;
}

extern "C" void kernel_launch(void* const* d_in, const int* in_sizes, int n_in,
                              void* d_out, int out_size, void* d_ws, size_t ws_size,
                              hipStream_t stream)
{
    (void)in_sizes; (void)n_in; (void)out_size; (void)ws_size;
    // d_in: 0=x, 1=wq_w,2=wq_b, 3=wk_w,4=wk_b, 5=wv_w,6=wv_b,
    //       7=vq_w,8=vq_b, 9=vk_w,10=vk_b, 11=vv_w,12=vv_b, 13=wo_w,14=wo_b
    bf16_t* base = (bf16_t*)d_ws;
    bf16_t* xbf  = base;                      // 2M
    bf16_t* vbf  = base + XN;                 // vq,vk,vv bf16: 3M
    bf16_t* wobf = vbf + 3 * WN;              // 1M
    bf16_t* wT   = wobf + WN;                 // wqT,wkT,wvT: 3M
    bf16_t* Wc   = wT + 3 * WN;               // combined weights: 3M
    float*  bqc  = (float*)(Wc + 3 * WN);     // 3*1024 f32
    bf16_t* q    = Wc + 3 * WN + 8192;        // 2M
    bf16_t* kc   = q + XN;                    // 2M
    bf16_t* vc   = kc + XN;                   // 2M
    bf16_t* y    = vc + XN;                   // 2M

    // 1) cast linear: x, vq_w, vk_w, vv_w, wo_w
    cast_k<<<dim3(1024), dim3(256), 0, stream>>>(
        (const float*)d_in[0], (const float*)d_in[7], (const float*)d_in[9],
        (const float*)d_in[11], (const float*)d_in[13], base);

    // 2) transpose inner weights wq,wk,wv -> bf16 wT
    trans_k<<<dim3(192), dim3(256), 0, stream>>>(
        (const float*)d_in[1], (const float*)d_in[3], (const float*)d_in[5], wT);

    // 3) combined biases: bqc[z] = V_z @ b_in_z + b_out_z
    biasc_k<<<dim3(768), dim3(256), 0, stream>>>(
        vbf, (const float*)d_in[2], (const float*)d_in[4], (const float*)d_in[6],
        (const float*)d_in[8], (const float*)d_in[10], (const float*)d_in[12], bqc);

    // 4) combine: Wc_z = V_z @ W_z  (A = V bf16, W = W_z^T)
    gemm_k<0, 64, false, 8, 16, 3><<<dim3(384), dim3(256), 0, stream>>>(
        vbf, vbf + WN, vbf + 2 * WN, wT, wT + WN, wT + 2 * WN,
        nullptr, nullptr, nullptr, Wc, Wc + WN, Wc + 2 * WN);

    // 5) QKV: q scaled natural; k/v fragment-order
    gemm_k<1, 128, true, 16, 8, 3><<<dim3(384), dim3(256), 0, stream>>>(
        xbf, xbf, xbf, Wc, Wc + WN, Wc + 2 * WN,
        bqc, bqc + 1024, bqc + 2048, q, kc, vc);

    // 6) attention + permuted scatter into y
    attn_k<<<dim3(4, 64, 2), dim3(512), 0, stream>>>(q, kc, vc, y);

    // 7) out = y @ wo^T + b (f32)
    gemm_k<2, 64, true, 16, 16, 1><<<dim3(256), dim3(256), 0, stream>>>(
        y, y, y, wobf, wobf, wobf,
        (const float*)d_in[14], nullptr, nullptr, d_out, d_out, d_out);
}

// Round 6
// 203.408 us; speedup vs baseline: 1.0048x; 1.0048x over previous
//
#include <hip/hip_runtime.h>
#include <hip/hip_bf16.h>
#include <stdint.h>

typedef __bf16 bf16_t;
typedef __bf16 bf16x8 __attribute__((ext_vector_type(8)));
typedef __bf16 bf16x4 __attribute__((ext_vector_type(4)));
typedef float f32x4 __attribute__((ext_vector_type(4)));
typedef float f32x16 __attribute__((ext_vector_type(16)));
typedef uint32_t u32x4 __attribute__((ext_vector_type(4)));

#define XN 2097152   // x elements (2*1024*1024)
#define WN 1048576   // each weight (1024*1024)

typedef __attribute__((address_space(1))) const uint8_t* gas_ptr;
typedef __attribute__((address_space(3))) uint8_t* las_ptr;

static __device__ __forceinline__ uint16_t bfbits(float f) {
    bf16_t b = (bf16_t)f;
    return __builtin_bit_cast(uint16_t, b);
}

// ---- fused prep: [0,1024) cast x,vq,vk,vv,wo -> bf16;
//                  [1024,1216) transpose wq,wk,wv -> bf16 wT;
//                  [1216,1984) combined bias bqc[z] = Vz(f32) @ b_in_z + b_out_z
// NOTE: biasc reads the f32 inputs directly — no dependency on the cast branch
// (fusing a dependency across blocks of one launch is a race: dispatch order undefined).
__global__ __launch_bounds__(256)
void prep_k(const float* __restrict__ x,
            const float* __restrict__ wq, const float* __restrict__ wk, const float* __restrict__ wv,
            const float* __restrict__ vq, const float* __restrict__ vk, const float* __restrict__ vv,
            const float* __restrict__ wo,
            const float* __restrict__ bq1, const float* __restrict__ bk1, const float* __restrict__ bv1,
            const float* __restrict__ bq2, const float* __restrict__ bk2, const float* __restrict__ bv2,
            bf16_t* __restrict__ castDst,   // x, vq, vk, vv, wo  (XN + 4*WN)
            bf16_t* __restrict__ wT,        // 3*WN transposed
            float* __restrict__ bqc)        // 3*1024
{
    __shared__ uint8_t tt[32768];
    const int bid = blockIdx.x;
    const int t = threadIdx.x;

    if (bid < 1024) {
        const int TOTC = (XN + 4 * WN) / 4;
        for (int c = bid * 256 + t; c < TOTC; c += 1024 * 256) {
            int el = c * 4;
            const float* s;
            if (el < XN) {
                s = x + el;
            } else {
                int r = el - XN;
                int wi = r >> 20;
                int off = r & (WN - 1);
                const float* wp = (wi == 0) ? vq : (wi == 1) ? vk : (wi == 2) ? vv : wo;
                s = wp + off;
            }
            float4 f = *(const float4*)s;
            bf16x4 o = { (bf16_t)f.x, (bf16_t)f.y, (bf16_t)f.z, (bf16_t)f.w };
            *(bf16x4*)(castDst + el) = o;
        }
    } else if (bid < 1216) {
        const int gid = bid - 1024;          // 192: 3 weights x 64 tiles
        const int w = gid >> 6, t6 = gid & 63;
        const int r0 = (t6 >> 3) * 128, c0 = (t6 & 7) * 128;
        const float* src = (w == 0) ? wq : (w == 1) ? wk : wv;
        bf16_t* dst = wT + (size_t)w * WN;

#pragma unroll
        for (int i = 0; i < 4; ++i) {
            const int lid = i * 256 + t;
            const int r4 = lid >> 5, c4 = lid & 31;
            const float* p = src + (size_t)(r0 + r4 * 4) * 1024 + c0 + c4 * 4;
            float4 a = *(const float4*)p;
            float4 b = *(const float4*)(p + 1024);
            float4 cv = *(const float4*)(p + 2048);
            float4 d = *(const float4*)(p + 3072);
            const float* af = (const float*)&a; const float* bf = (const float*)&b;
            const float* cf = (const float*)&cv; const float* df = (const float*)&d;
#pragma unroll
            for (int j = 0; j < 4; ++j) {
                const int cc = c4 * 4 + j;
                const int g = r4 >> 1, h = r4 & 1;
                bf16x4 o = { (bf16_t)af[j], (bf16_t)bf[j], (bf16_t)cf[j], (bf16_t)df[j] };
                *(bf16x4*)(tt + cc * 256 + ((g ^ (cc & 15)) << 4) + h * 8) = o;
            }
        }
        __syncthreads();
#pragma unroll
        for (int j = 0; j < 8; ++j) {
            const int lid = j * 256 + t;
            const int cc = lid >> 4, g = lid & 15;
            bf16x8 v = *(const bf16x8*)(tt + cc * 256 + ((g ^ (cc & 15)) << 4));
            *(bf16x8*)(dst + (size_t)(c0 + cc) * 1024 + r0 + g * 8) = v;
        }
    } else {
        const int vbid = bid - 1216;         // 768 = 3 x 256
        const int z = vbid >> 8;
        const int wave = t >> 6, lane = t & 63;
        const int o = (vbid & 255) * 4 + wave;
        const float* bi = (z == 0) ? bq1 : (z == 1) ? bk1 : bv1;
        const float* bo = (z == 0) ? bq2 : (z == 1) ? bk2 : bv2;
        const float* row = ((z == 0) ? vq : (z == 1) ? vk : vv) + (size_t)o * 1024;

        float sum = 0.f;
#pragma unroll
        for (int i = 0; i < 2; ++i) {
            const int j = (lane + 64 * i) * 8;
            float4 r0 = *(const float4*)(row + j);
            float4 r1 = *(const float4*)(row + j + 4);
            float4 f0 = *(const float4*)(bi + j);
            float4 f1 = *(const float4*)(bi + j + 4);
            sum += r0.x * f0.x + r0.y * f0.y + r0.z * f0.z + r0.w * f0.w;
            sum += r1.x * f1.x + r1.y * f1.y + r1.z * f1.z + r1.w * f1.w;
        }
#pragma unroll
        for (int off = 1; off < 64; off <<= 1) sum += __shfl_xor(sum, off, 64);
        if (lane == 0) bqc[z * 1024 + o] = sum + bo[o];
    }
}

// ---- MFMA GEMM, 2-phase double-buffered (T3-minimum): C = A @ W^T (+ bias)
// BM=128, BN in {64,128}. Per K-step: issue next-tile global_load_lds BEFORE
// ds_read+MFMA of current tile; single vmcnt-drain barrier after compute.
// EPI 0: bf16 natural. EPI 1: z0 scaled-natural / z1 K-frag / z2 V-frag.
// EPI 2: f32 natural.
#define QSCALE 0.36067376022224085f   // 0.25 * log2(e)

template<int EPI, int BN, bool HASBIAS, int MT, int NT, int NZ>
__global__ __launch_bounds__(256)
void gemm_k(const bf16_t* __restrict__ A0, const bf16_t* __restrict__ A1, const bf16_t* __restrict__ A2,
            const bf16_t* __restrict__ W0, const bf16_t* __restrict__ W1, const bf16_t* __restrict__ W2,
            const float* __restrict__ bias0, const float* __restrict__ bias1, const float* __restrict__ bias2,
            void* O0, void* O1, void* O2)
{
    constexpr int NACC = BN / 32;
    constexpr int TOT = MT * NT * NZ;
    const int bid = blockIdx.x;
    const int swz = (bid & 7) * (TOT / 8) + (bid >> 3);   // XCD-bijective
    const int z = (NZ == 1) ? 0 : swz / (MT * NT);
    const int rr = swz % (MT * NT);
    const int mt = rr / NT, nt = rr % NT;

    const bf16_t* A = (z == 0) ? A0 : (z == 1) ? A1 : A2;
    const bf16_t* W = (z == 0) ? W0 : (z == 1) ? W1 : W2;
    const float* bias = (z == 0) ? bias0 : (z == 1) ? bias1 : bias2;
    void* Ov = (z == 0) ? O0 : (z == 1) ? O1 : O2;

    __shared__ bf16_t As[2][128 * 64];
    __shared__ bf16_t Bs[2][BN * 64];

    const int tid = threadIdx.x;
    const int lane = tid & 63, wave = tid >> 6;
    const int lo = lane & 15, hi = lane >> 4;
    const int wr = wave >> 1, wc = wave & 1;
    const int m0 = mt * 128, n0 = nt * BN;

    auto stage = [&](int buf, int kt) {
        const int K0 = kt * 64;
#pragma unroll
        for (int i = 0; i < 4; ++i) {
            const int cbase = i * 256 + wave * 64;
            const int c = cbase + lane;
            const int row = c >> 3, ko = c & 7;
            const bf16_t* ga = A + (size_t)(m0 + row) * 1024 + K0 + ko * 8;
            __builtin_amdgcn_global_load_lds((gas_ptr)ga, (las_ptr)(&As[buf][cbase * 8]), 16, 0, 0);
        }
#pragma unroll
        for (int i = 0; i < NACC; ++i) {
            const int cbase = i * 256 + wave * 64;
            const int c = cbase + lane;
            const int row = c >> 3, ko = c & 7;
            const bf16_t* gb = W + (size_t)(n0 + row) * 1024 + K0 + ko * 8;
            __builtin_amdgcn_global_load_lds((gas_ptr)gb, (las_ptr)(&Bs[buf][cbase * 8]), 16, 0, 0);
        }
    };

    f32x4 acc[4][NACC] = {};

    stage(0, 0);
    __syncthreads();   // drain prologue loads

    for (int kt = 0; kt < 16; ++kt) {
        const int cur = kt & 1;
        if (kt < 15) stage(cur ^ 1, kt + 1);   // prefetch next tile (in flight over compute)
#pragma unroll
        for (int kk = 0; kk < 2; ++kk) {
            const int kb = kk * 32 + hi * 8;
            bf16x8 af[4], bfr[NACC];
#pragma unroll
            for (int m = 0; m < 4; ++m) af[m] = *(const bf16x8*)&As[cur][(wr * 64 + m * 16 + lo) * 64 + kb];
#pragma unroll
            for (int n = 0; n < NACC; ++n) bfr[n] = *(const bf16x8*)&Bs[cur][(wc * (BN / 2) + n * 16 + lo) * 64 + kb];
#pragma unroll
            for (int m = 0; m < 4; ++m)
#pragma unroll
                for (int n = 0; n < NACC; ++n)
                    acc[m][n] = __builtin_amdgcn_mfma_f32_16x16x32_bf16(af[m], bfr[n], acc[m][n], 0, 0, 0);
        }
        __syncthreads();   // compiler drains vmcnt here -> next tile ready; cur buffer free
    }

#pragma unroll
    for (int n = 0; n < NACC; ++n) {
        const int col = n0 + wc * (BN / 2) + n * 16 + lo;
        const float bv = HASBIAS ? bias[col] : 0.f;
#pragma unroll
        for (int m = 0; m < 4; ++m) {
            const int r0 = m0 + wr * 64 + m * 16 + hi * 4;
            if (EPI == 2) {
                float* O = (float*)Ov;
#pragma unroll
                for (int r = 0; r < 4; ++r)
                    O[(size_t)(r0 + r) * 1024 + col] = acc[m][n][r] + bv;
            } else if (EPI == 0 || z == 0) {
                bf16_t* O = (bf16_t*)Ov;
                const float sc = (EPI == 1) ? QSCALE : 1.0f;
#pragma unroll
                for (int r = 0; r < 4; ++r)
                    O[(size_t)(r0 + r) * 1024 + col] = (bf16_t)((acc[m][n][r] + bv) * sc);
            } else if (z == 1) {
                // K fragment-order: chunk C = (s>>5)*64 + (h>>3)*32 + (s&31), elem C*8 + (h&7)
                bf16_t* O = (bf16_t*)Ov;
                const int cch = col >> 4, h = col & 15;
                const int bb = r0 >> 10;
                const size_t sb = (size_t)(cch * 2 + bb) * 16384;
#pragma unroll
                for (int r = 0; r < 4; ++r) {
                    const int ss = (r0 + r) & 1023;
                    const int C = ((ss >> 5) << 6) + ((h >> 3) << 5) + (ss & 31);
                    O[sb + C * 8 + (h & 7)] = (bf16_t)(acc[m][n][r] + bv);
                }
            } else {
                // V fragment-order: C = (s>>5)*64 + ((s>>4)&1)*32 + ((s>>3)&1)*16 + h, elem C*8 + (s&7)
                bf16_t* O = (bf16_t*)Ov;
                const int cch = col >> 4, h = col & 15;
                const int bb = r0 >> 10;
                const int s0 = r0 & 1023;
                const int C = ((s0 >> 5) << 6) + (((s0 >> 4) & 1) << 5) + (((s0 >> 3) & 1) << 4) + h;
                bf16x4 pv = { (bf16_t)(acc[m][n][0] + bv), (bf16_t)(acc[m][n][1] + bv),
                              (bf16_t)(acc[m][n][2] + bv), (bf16_t)(acc[m][n][3] + bv) };
                *(bf16x4*)(O + (size_t)(cch * 2 + bb) * 16384 + C * 8 + (s0 & 7)) = pv;
            }
        }
    }
}

// ---- attention: per (c,b), K/V staged in LDS fragment-order (unchanged)
__global__ __launch_bounds__(512)
void attn_k(const bf16_t* __restrict__ qg, const bf16_t* __restrict__ kfr,
            const bf16_t* __restrict__ vfr, bf16_t* __restrict__ y)
{
    __shared__ bf16_t lds[32768];

    const int c = blockIdx.y, b = blockIdx.z;
    const int tid = threadIdx.x;
    const int lane = tid & 63, wave = tid >> 6;
    const int l31 = lane & 31, hi = lane >> 5;
    const int s = blockIdx.x * 256 + wave * 32 + l31;

    const bf16_t* kb = kfr + (size_t)(c * 2 + b) * 16384;
    const bf16_t* vb = vfr + (size_t)(c * 2 + b) * 16384;
#pragma unroll
    for (int i = 0; i < 4; ++i) {
        const int cbase = i * 512 + wave * 64;
        __builtin_amdgcn_global_load_lds((gas_ptr)(kb + (cbase + lane) * 8),
                                         (las_ptr)((uint8_t*)lds + cbase * 16), 16, 0, 0);
        __builtin_amdgcn_global_load_lds((gas_ptr)(vb + (cbase + lane) * 8),
                                         (las_ptr)((uint8_t*)lds + 32768 + cbase * 16), 16, 0, 0);
    }

    bf16x8 qf = *(const bf16x8*)(qg + ((size_t)(b * 1024 + s)) * 1024 + c * 16 + hi * 8);

    __syncthreads();

    f32x16 oacc = {};
    const f32x16 z16 = {};
    float den = 0.f;
    const int vslot = ((lane >> 5) * 16 + (lane & 15)) * 8;

    for (int jt = 0; jt < 32; ++jt) {
        bf16x8 kf  = *(const bf16x8*)&lds[jt * 512 + lane * 8];
        bf16x8 vf0 = *(const bf16x8*)&lds[16384 + jt * 512 + vslot];
        bf16x8 vf1 = *(const bf16x8*)&lds[16384 + jt * 512 + 256 + vslot];

        f32x16 st = __builtin_amdgcn_mfma_f32_32x32x16_bf16(kf, qf, z16, 0, 0, 0);

        float p[16];
#pragma unroll
        for (int r = 0; r < 16; ++r) { p[r] = __builtin_amdgcn_exp2f(st[r]); den += p[r]; }

        uint32_t pk[8];
#pragma unroll
        for (int w = 0; w < 8; ++w)
            pk[w] = (uint32_t)bfbits(p[2 * w]) | ((uint32_t)bfbits(p[2 * w + 1]) << 16);

        asm("v_permlane32_swap_b32 %0, %1" : "+v"(pk[0]), "+v"(pk[2]));
        asm("v_permlane32_swap_b32 %0, %1" : "+v"(pk[1]), "+v"(pk[3]));
        asm("v_permlane32_swap_b32 %0, %1" : "+v"(pk[4]), "+v"(pk[6]));
        asm("v_permlane32_swap_b32 %0, %1" : "+v"(pk[5]), "+v"(pk[7]));

        u32x4 f0v = { pk[0], pk[1], pk[2], pk[3] };
        u32x4 f1v = { pk[4], pk[5], pk[6], pk[7] };
        bf16x8 pf0 = __builtin_bit_cast(bf16x8, f0v);
        bf16x8 pf1 = __builtin_bit_cast(bf16x8, f1v);

        oacc = __builtin_amdgcn_mfma_f32_32x32x16_bf16(vf0, pf0, oacc, 0, 0, 0);
        oacc = __builtin_amdgcn_mfma_f32_32x32x16_bf16(vf1, pf1, oacc, 0, 0, 0);
    }

    float dtot = den + __shfl_xor(den, 32, 64);
    float rinv = 1.0f / dtot;

    const int bo = (c >> 1) & 1;
    const int so = (c & 1) * 512 + b * 256 + (s >> 2);
    const int f0i = (c >> 2) * 64 + (s & 3) * 16;
    bf16_t* yb = y + ((size_t)bo * 1024 + so) * 1024 + f0i + 4 * hi;
    bf16x4 o1 = { (bf16_t)(oacc[0] * rinv), (bf16_t)(oacc[1] * rinv),
                  (bf16_t)(oacc[2] * rinv), (bf16_t)(oacc[3] * rinv) };
    *(bf16x4*)(yb) = o1;
    bf16x4 o2 = { (bf16_t)(oacc[4] * rinv), (bf16_t)(oacc[5] * rinv),
                  (bf16_t)(oacc[6] * rinv), (bf16_t)(oacc[7] * rinv) };
    *(bf16x4*)(yb + 8) = o2;
}

extern "C" void kernel_launch(void* const* d_in, const int* in_sizes, int n_in,
                              void* d_out, int out_size, void* d_ws, size_t ws_size,
                              hipStream_t stream)
{
    (void)in_sizes; (void)n_in; (void)out_size; (void)ws_size;
    // d_in: 0=x, 1=wq_w,2=wq_b, 3=wk_w,4=wk_b, 5=wv_w,6=wv_b,
    //       7=vq_w,8=vq_b, 9=vk_w,10=vk_b, 11=vv_w,12=vv_b, 13=wo_w,14=wo_b
    bf16_t* base = (bf16_t*)d_ws;
    bf16_t* xbf  = base;                      // 2M
    bf16_t* vbf  = base + XN;                 // vq,vk,vv bf16: 3M
    bf16_t* wobf = vbf + 3 * WN;              // 1M
    bf16_t* wT   = wobf + WN;                 // wqT,wkT,wvT: 3M
    bf16_t* Wc   = wT + 3 * WN;               // combined weights: 3M
    float*  bqc  = (float*)(Wc + 3 * WN);     // 3*1024 f32
    bf16_t* q    = Wc + 3 * WN + 8192;        // 2M
    bf16_t* kc   = q + XN;                    // 2M
    bf16_t* vc   = kc + XN;                   // 2M
    bf16_t* y    = vc + XN;                   // 2M

    // 1) fused prep: cast + transpose + combined bias (bias from f32 inputs)
    prep_k<<<dim3(1984), dim3(256), 0, stream>>>(
        (const float*)d_in[0],
        (const float*)d_in[1], (const float*)d_in[3], (const float*)d_in[5],
        (const float*)d_in[7], (const float*)d_in[9], (const float*)d_in[11],
        (const float*)d_in[13],
        (const float*)d_in[2], (const float*)d_in[4], (const float*)d_in[6],
        (const float*)d_in[8], (const float*)d_in[10], (const float*)d_in[12],
        base, wT, bqc);

    // 2) combine: Wc_z = V_z @ W_z
    gemm_k<0, 64, false, 8, 16, 3><<<dim3(384), dim3(256), 0, stream>>>(
        vbf, vbf + WN, vbf + 2 * WN, wT, wT + WN, wT + 2 * WN,
        nullptr, nullptr, nullptr, Wc, Wc + WN, Wc + 2 * WN);

    // 3) QKV: q scaled natural; k/v fragment-order
    gemm_k<1, 128, true, 16, 8, 3><<<dim3(384), dim3(256), 0, stream>>>(
        xbf, xbf, xbf, Wc, Wc + WN, Wc + 2 * WN,
        bqc, bqc + 1024, bqc + 2048, q, kc, vc);

    // 4) attention + permuted scatter into y
    attn_k<<<dim3(4, 64, 2), dim3(512), 0, stream>>>(q, kc, vc, y);

    // 5) out = y @ wo^T + b (f32)
    gemm_k<2, 64, true, 16, 16, 1><<<dim3(256), dim3(256), 0, stream>>>(
        y, y, y, wobf, wobf, wobf,
        (const float*)d_in[14], nullptr, nullptr, d_out, d_out, d_out);
}

// Round 7
// 199.852 us; speedup vs baseline: 1.0227x; 1.0178x over previous
//
#include <hip/hip_runtime.h>
#include <hip/hip_bf16.h>
#include <stdint.h>

typedef __bf16 bf16_t;
typedef __bf16 bf16x8 __attribute__((ext_vector_type(8)));
typedef __bf16 bf16x4 __attribute__((ext_vector_type(4)));
typedef float f32x4 __attribute__((ext_vector_type(4)));
typedef float f32x16 __attribute__((ext_vector_type(16)));
typedef uint32_t u32x4 __attribute__((ext_vector_type(4)));

#define XN 2097152   // x elements (2*1024*1024)
#define WN 1048576   // each weight (1024*1024)

typedef __attribute__((address_space(1))) const uint8_t* gas_ptr;
typedef __attribute__((address_space(3))) uint8_t* las_ptr;

static __device__ __forceinline__ uint16_t bfbits(float f) {
    bf16_t b = (bf16_t)f;
    return __builtin_bit_cast(uint16_t, b);
}

// ---------- shared device pieces ----------

// cast 1024 f32 -> bf16 per block (4 per thread), cid in [0, nel/1024)
static __device__ __forceinline__ void dev_cast_blk(int cid, int t,
                                                    const float* __restrict__ src,
                                                    bf16_t* __restrict__ dst)
{
    const int el = cid * 1024 + t * 4;
    float4 f = *(const float4*)(src + el);
    bf16x4 o = { (bf16_t)f.x, (bf16_t)f.y, (bf16_t)f.z, (bf16_t)f.w };
    *(bf16x4*)(dst + el) = o;
}

// ---- MFMA GEMM body, 2-phase double-buffered: C = A @ W^T (+ bias)
// 4 waves in 2x2; wave tile (BM/2)x(BN/2); MACC=BM/32, NACC=BN/32 16x16 frags.
// EPI 0: bf16 natural. EPI 1: z0 scaled-natural / z1 K-frag / z2 V-frag. EPI 2: f32.
#define QSCALE 0.36067376022224085f   // 0.25 * log2(e)

template<int EPI, int BM, int BN, bool HASBIAS, int MT, int NT, int NZ>
static __device__ __forceinline__
void gemm_body(int bid, bf16_t* As, bf16_t* Bs,
               const bf16_t* __restrict__ A0, const bf16_t* __restrict__ A1, const bf16_t* __restrict__ A2,
               const bf16_t* __restrict__ W0, const bf16_t* __restrict__ W1, const bf16_t* __restrict__ W2,
               const float* __restrict__ bias0, const float* __restrict__ bias1, const float* __restrict__ bias2,
               void* O0, void* O1, void* O2)
{
    constexpr int MACC = BM / 32, NACC = BN / 32;
    constexpr int TOT = MT * NT * NZ;
    const int swz = (bid & 7) * (TOT / 8) + (bid >> 3);   // XCD-bijective (TOT%8==0)
    const int z = (NZ == 1) ? 0 : swz / (MT * NT);
    const int rr = swz % (MT * NT);
    const int mt = rr / NT, nt = rr % NT;

    const bf16_t* A = (z == 0) ? A0 : (z == 1) ? A1 : A2;
    const bf16_t* W = (z == 0) ? W0 : (z == 1) ? W1 : W2;
    const float* bias = (z == 0) ? bias0 : (z == 1) ? bias1 : bias2;
    void* Ov = (z == 0) ? O0 : (z == 1) ? O1 : O2;

    const int tid = threadIdx.x;
    const int lane = tid & 63, wave = tid >> 6;
    const int lo = lane & 15, hi = lane >> 4;
    const int wr = wave >> 1, wc = wave & 1;
    const int m0 = mt * BM, n0 = nt * BN;

    bf16_t* AsB[2] = { As, As + BM * 64 };
    bf16_t* BsB[2] = { Bs, Bs + BN * 64 };

    auto stage = [&](int buf, int kt) {
        const int K0 = kt * 64;
#pragma unroll
        for (int i = 0; i < MACC; ++i) {
            const int cbase = i * 256 + wave * 64;
            const int c = cbase + lane;
            const int row = c >> 3, ko = c & 7;
            const bf16_t* ga = A + (size_t)(m0 + row) * 1024 + K0 + ko * 8;
            __builtin_amdgcn_global_load_lds((gas_ptr)ga, (las_ptr)(AsB[buf] + cbase * 8), 16, 0, 0);
        }
#pragma unroll
        for (int i = 0; i < NACC; ++i) {
            const int cbase = i * 256 + wave * 64;
            const int c = cbase + lane;
            const int row = c >> 3, ko = c & 7;
            const bf16_t* gb = W + (size_t)(n0 + row) * 1024 + K0 + ko * 8;
            __builtin_amdgcn_global_load_lds((gas_ptr)gb, (las_ptr)(BsB[buf] + cbase * 8), 16, 0, 0);
        }
    };

    f32x4 acc[MACC][NACC] = {};

    stage(0, 0);
    __syncthreads();   // drain prologue loads

    for (int kt = 0; kt < 16; ++kt) {
        const int cur = kt & 1;
        if (kt < 15) stage(cur ^ 1, kt + 1);   // prefetch next tile over compute
#pragma unroll
        for (int kk = 0; kk < 2; ++kk) {
            const int kb = kk * 32 + hi * 8;
            bf16x8 af[MACC], bfr[NACC];
#pragma unroll
            for (int m = 0; m < MACC; ++m) af[m] = *(const bf16x8*)&AsB[cur][(wr * (BM / 2) + m * 16 + lo) * 64 + kb];
#pragma unroll
            for (int n = 0; n < NACC; ++n) bfr[n] = *(const bf16x8*)&BsB[cur][(wc * (BN / 2) + n * 16 + lo) * 64 + kb];
#pragma unroll
            for (int m = 0; m < MACC; ++m)
#pragma unroll
                for (int n = 0; n < NACC; ++n)
                    acc[m][n] = __builtin_amdgcn_mfma_f32_16x16x32_bf16(af[m], bfr[n], acc[m][n], 0, 0, 0);
        }
        __syncthreads();   // per-wave vmcnt drained at barrier -> next tile ready; cur free
    }

#pragma unroll
    for (int n = 0; n < NACC; ++n) {
        const int col = n0 + wc * (BN / 2) + n * 16 + lo;
        const float bv = HASBIAS ? bias[col] : 0.f;
#pragma unroll
        for (int m = 0; m < MACC; ++m) {
            const int r0 = m0 + wr * (BM / 2) + m * 16 + hi * 4;
            if (EPI == 2) {
                float* O = (float*)Ov;
#pragma unroll
                for (int r = 0; r < 4; ++r)
                    O[(size_t)(r0 + r) * 1024 + col] = acc[m][n][r] + bv;
            } else if (EPI == 0 || z == 0) {
                bf16_t* O = (bf16_t*)Ov;
                const float sc = (EPI == 1) ? QSCALE : 1.0f;
#pragma unroll
                for (int r = 0; r < 4; ++r)
                    O[(size_t)(r0 + r) * 1024 + col] = (bf16_t)((acc[m][n][r] + bv) * sc);
            } else if (z == 1) {
                // K fragment-order: chunk C = (s>>5)*64 + (h>>3)*32 + (s&31), elem C*8 + (h&7)
                bf16_t* O = (bf16_t*)Ov;
                const int cch = col >> 4, h = col & 15;
                const int bb = r0 >> 10;
                const size_t sb = (size_t)(cch * 2 + bb) * 16384;
#pragma unroll
                for (int r = 0; r < 4; ++r) {
                    const int ss = (r0 + r) & 1023;
                    const int C = ((ss >> 5) << 6) + ((h >> 3) << 5) + (ss & 31);
                    O[sb + C * 8 + (h & 7)] = (bf16_t)(acc[m][n][r] + bv);
                }
            } else {
                // V fragment-order: C = (s>>5)*64 + ((s>>4)&1)*32 + ((s>>3)&1)*16 + h, elem C*8 + (s&7)
                bf16_t* O = (bf16_t*)Ov;
                const int cch = col >> 4, h = col & 15;
                const int bb = r0 >> 10;
                const int s0 = r0 & 1023;
                const int C = ((s0 >> 5) << 6) + (((s0 >> 4) & 1) << 5) + (((s0 >> 3) & 1) << 4) + h;
                bf16x4 pv = { (bf16_t)(acc[m][n][0] + bv), (bf16_t)(acc[m][n][1] + bv),
                              (bf16_t)(acc[m][n][2] + bv), (bf16_t)(acc[m][n][3] + bv) };
                *(bf16x4*)(O + (size_t)(cch * 2 + bb) * 16384 + C * 8 + (s0 & 7)) = pv;
            }
        }
    }
}

// ---- prep: [0,192) transpose wq,wk,wv -> bf16 wT; [192, 3264) cast vq,vk,vv -> vbf
__global__ __launch_bounds__(256)
void prep_k(const float* __restrict__ wq, const float* __restrict__ wk, const float* __restrict__ wv,
            const float* __restrict__ vq, const float* __restrict__ vk, const float* __restrict__ vv,
            bf16_t* __restrict__ wT, bf16_t* __restrict__ vbf)
{
    __shared__ uint8_t tt[32768];
    const int bid = blockIdx.x;
    const int t = threadIdx.x;

    if (bid < 192) {
        const int w = bid >> 6, t6 = bid & 63;
        const int r0 = (t6 >> 3) * 128, c0 = (t6 & 7) * 128;
        const float* src = (w == 0) ? wq : (w == 1) ? wk : wv;
        bf16_t* dst = wT + (size_t)w * WN;

#pragma unroll
        for (int i = 0; i < 4; ++i) {
            const int lid = i * 256 + t;
            const int r4 = lid >> 5, c4 = lid & 31;
            const float* p = src + (size_t)(r0 + r4 * 4) * 1024 + c0 + c4 * 4;
            float4 a = *(const float4*)p;
            float4 b = *(const float4*)(p + 1024);
            float4 cv = *(const float4*)(p + 2048);
            float4 d = *(const float4*)(p + 3072);
            const float* af = (const float*)&a; const float* bf = (const float*)&b;
            const float* cf = (const float*)&cv; const float* df = (const float*)&d;
#pragma unroll
            for (int j = 0; j < 4; ++j) {
                const int cc = c4 * 4 + j;
                const int g = r4 >> 1, h = r4 & 1;
                bf16x4 o = { (bf16_t)af[j], (bf16_t)bf[j], (bf16_t)cf[j], (bf16_t)df[j] };
                *(bf16x4*)(tt + cc * 256 + ((g ^ (cc & 15)) << 4) + h * 8) = o;
            }
        }
        __syncthreads();
#pragma unroll
        for (int j = 0; j < 8; ++j) {
            const int lid = j * 256 + t;
            const int cc = lid >> 4, g = lid & 15;
            bf16x8 v = *(const bf16x8*)(tt + cc * 256 + ((g ^ (cc & 15)) << 4));
            *(bf16x8*)(dst + (size_t)(c0 + cc) * 1024 + r0 + g * 8) = v;
        }
    } else {
        const int cid = bid - 192;           // 3072 blocks: 3*WN elements
        const int el = cid * 1024;
        const int wi = el >> 20;
        const float* src = (wi == 0) ? vq : (wi == 1) ? vk : vv;
        dev_cast_blk(cid & 1023, t, src, vbf + (size_t)wi * WN);
    }
}

// ---- fused combine launch:
// [0,768)       gemm 64x64: Wc_z = V_z @ W_z   (3 x 1024^3)
// [768,2816)    cast x -> xbf
// [2816,3840)   cast wo -> wobf
// [3840,4608)   combined bias bqc[z] = Vz(f32) @ b_in_z + b_out_z
// All filler blocks read only f32 inputs / write buffers consumed by LATER launches
// (no intra-launch dependency -> no dispatch-order race).
__global__ __launch_bounds__(256)
void combine_k(const bf16_t* __restrict__ vbf, const bf16_t* __restrict__ wT,
               bf16_t* __restrict__ Wc,
               const float* __restrict__ x, bf16_t* __restrict__ xbf,
               const float* __restrict__ wo, bf16_t* __restrict__ wobf,
               const float* __restrict__ vq, const float* __restrict__ vk, const float* __restrict__ vv,
               const float* __restrict__ bq1, const float* __restrict__ bk1, const float* __restrict__ bv1,
               const float* __restrict__ bq2, const float* __restrict__ bk2, const float* __restrict__ bv2,
               float* __restrict__ bqc)
{
    __shared__ bf16_t As[2 * 64 * 64];
    __shared__ bf16_t Bs[2 * 64 * 64];
    const int bid = blockIdx.x;
    const int t = threadIdx.x;

    if (bid < 768) {
        gemm_body<0, 64, 64, false, 16, 16, 3>(bid, As, Bs,
            vbf, vbf + WN, vbf + 2 * WN, wT, wT + WN, wT + 2 * WN,
            nullptr, nullptr, nullptr, Wc, Wc + WN, Wc + 2 * WN);
    } else if (bid < 2816) {
        dev_cast_blk(bid - 768, t, x, xbf);
    } else if (bid < 3840) {
        dev_cast_blk(bid - 2816, t, wo, wobf);
    } else {
        const int vbid = bid - 3840;         // 768 = 3 x 256
        const int z = vbid >> 8;
        const int wave = t >> 6, lane = t & 63;
        const int o = (vbid & 255) * 4 + wave;
        const float* bi = (z == 0) ? bq1 : (z == 1) ? bk1 : bv1;
        const float* bo = (z == 0) ? bq2 : (z == 1) ? bk2 : bv2;
        const float* row = ((z == 0) ? vq : (z == 1) ? vk : vv) + (size_t)o * 1024;

        float sum = 0.f;
#pragma unroll
        for (int i = 0; i < 2; ++i) {
            const int j = (lane + 64 * i) * 8;
            float4 r0 = *(const float4*)(row + j);
            float4 r1 = *(const float4*)(row + j + 4);
            float4 f0 = *(const float4*)(bi + j);
            float4 f1 = *(const float4*)(bi + j + 4);
            sum += r0.x * f0.x + r0.y * f0.y + r0.z * f0.z + r0.w * f0.w;
            sum += r1.x * f1.x + r1.y * f1.y + r1.z * f1.z + r1.w * f1.w;
        }
#pragma unroll
        for (int off = 1; off < 64; off <<= 1) sum += __shfl_xor(sum, off, 64);
        if (lane == 0) bqc[z * 1024 + o] = sum + bo[o];
    }
}

// ---- standalone GEMM kernel (QKV and stage3)
template<int EPI, int BM, int BN, bool HASBIAS, int MT, int NT, int NZ>
__global__ __launch_bounds__(256)
void gemm_k(const bf16_t* __restrict__ A0, const bf16_t* __restrict__ A1, const bf16_t* __restrict__ A2,
            const bf16_t* __restrict__ W0, const bf16_t* __restrict__ W1, const bf16_t* __restrict__ W2,
            const float* __restrict__ bias0, const float* __restrict__ bias1, const float* __restrict__ bias2,
            void* O0, void* O1, void* O2)
{
    __shared__ bf16_t As[2 * BM * 64];
    __shared__ bf16_t Bs[2 * BN * 64];
    gemm_body<EPI, BM, BN, HASBIAS, MT, NT, NZ>(blockIdx.x, As, Bs,
        A0, A1, A2, W0, W1, W2, bias0, bias1, bias2, O0, O1, O2);
}

// ---- attention: per (c,b), K/V staged in LDS fragment-order (unchanged)
__global__ __launch_bounds__(512)
void attn_k(const bf16_t* __restrict__ qg, const bf16_t* __restrict__ kfr,
            const bf16_t* __restrict__ vfr, bf16_t* __restrict__ y)
{
    __shared__ bf16_t lds[32768];

    const int c = blockIdx.y, b = blockIdx.z;
    const int tid = threadIdx.x;
    const int lane = tid & 63, wave = tid >> 6;
    const int l31 = lane & 31, hi = lane >> 5;
    const int s = blockIdx.x * 256 + wave * 32 + l31;

    const bf16_t* kb = kfr + (size_t)(c * 2 + b) * 16384;
    const bf16_t* vb = vfr + (size_t)(c * 2 + b) * 16384;
#pragma unroll
    for (int i = 0; i < 4; ++i) {
        const int cbase = i * 512 + wave * 64;
        __builtin_amdgcn_global_load_lds((gas_ptr)(kb + (cbase + lane) * 8),
                                         (las_ptr)((uint8_t*)lds + cbase * 16), 16, 0, 0);
        __builtin_amdgcn_global_load_lds((gas_ptr)(vb + (cbase + lane) * 8),
                                         (las_ptr)((uint8_t*)lds + 32768 + cbase * 16), 16, 0, 0);
    }

    bf16x8 qf = *(const bf16x8*)(qg + ((size_t)(b * 1024 + s)) * 1024 + c * 16 + hi * 8);

    __syncthreads();

    f32x16 oacc = {};
    const f32x16 z16 = {};
    float den = 0.f;
    const int vslot = ((lane >> 5) * 16 + (lane & 15)) * 8;

    for (int jt = 0; jt < 32; ++jt) {
        bf16x8 kf  = *(const bf16x8*)&lds[jt * 512 + lane * 8];
        bf16x8 vf0 = *(const bf16x8*)&lds[16384 + jt * 512 + vslot];
        bf16x8 vf1 = *(const bf16x8*)&lds[16384 + jt * 512 + 256 + vslot];

        f32x16 st = __builtin_amdgcn_mfma_f32_32x32x16_bf16(kf, qf, z16, 0, 0, 0);

        float p[16];
#pragma unroll
        for (int r = 0; r < 16; ++r) { p[r] = __builtin_amdgcn_exp2f(st[r]); den += p[r]; }

        uint32_t pk[8];
#pragma unroll
        for (int w = 0; w < 8; ++w)
            pk[w] = (uint32_t)bfbits(p[2 * w]) | ((uint32_t)bfbits(p[2 * w + 1]) << 16);

        asm("v_permlane32_swap_b32 %0, %1" : "+v"(pk[0]), "+v"(pk[2]));
        asm("v_permlane32_swap_b32 %0, %1" : "+v"(pk[1]), "+v"(pk[3]));
        asm("v_permlane32_swap_b32 %0, %1" : "+v"(pk[4]), "+v"(pk[6]));
        asm("v_permlane32_swap_b32 %0, %1" : "+v"(pk[5]), "+v"(pk[7]));

        u32x4 f0v = { pk[0], pk[1], pk[2], pk[3] };
        u32x4 f1v = { pk[4], pk[5], pk[6], pk[7] };
        bf16x8 pf0 = __builtin_bit_cast(bf16x8, f0v);
        bf16x8 pf1 = __builtin_bit_cast(bf16x8, f1v);

        oacc = __builtin_amdgcn_mfma_f32_32x32x16_bf16(vf0, pf0, oacc, 0, 0, 0);
        oacc = __builtin_amdgcn_mfma_f32_32x32x16_bf16(vf1, pf1, oacc, 0, 0, 0);
    }

    float dtot = den + __shfl_xor(den, 32, 64);
    float rinv = 1.0f / dtot;

    const int bo = (c >> 1) & 1;
    const int so = (c & 1) * 512 + b * 256 + (s >> 2);
    const int f0i = (c >> 2) * 64 + (s & 3) * 16;
    bf16_t* yb = y + ((size_t)bo * 1024 + so) * 1024 + f0i + 4 * hi;
    bf16x4 o1 = { (bf16_t)(oacc[0] * rinv), (bf16_t)(oacc[1] * rinv),
                  (bf16_t)(oacc[2] * rinv), (bf16_t)(oacc[3] * rinv) };
    *(bf16x4*)(yb) = o1;
    bf16x4 o2 = { (bf16_t)(oacc[4] * rinv), (bf16_t)(oacc[5] * rinv),
                  (bf16_t)(oacc[6] * rinv), (bf16_t)(oacc[7] * rinv) };
    *(bf16x4*)(yb + 8) = o2;
}

extern "C" void kernel_launch(void* const* d_in, const int* in_sizes, int n_in,
                              void* d_out, int out_size, void* d_ws, size_t ws_size,
                              hipStream_t stream)
{
    (void)in_sizes; (void)n_in; (void)out_size; (void)ws_size;
    // d_in: 0=x, 1=wq_w,2=wq_b, 3=wk_w,4=wk_b, 5=wv_w,6=wv_b,
    //       7=vq_w,8=vq_b, 9=vk_w,10=vk_b, 11=vv_w,12=vv_b, 13=wo_w,14=wo_b
    bf16_t* base = (bf16_t*)d_ws;
    bf16_t* xbf  = base;                      // 2M
    bf16_t* vbf  = base + XN;                 // vq,vk,vv bf16: 3M
    bf16_t* wobf = vbf + 3 * WN;              // 1M
    bf16_t* wT   = wobf + WN;                 // wqT,wkT,wvT: 3M
    bf16_t* Wc   = wT + 3 * WN;               // combined weights: 3M
    float*  bqc  = (float*)(Wc + 3 * WN);     // 3*1024 f32
    bf16_t* q    = Wc + 3 * WN + 8192;        // 2M
    bf16_t* kc   = q + XN;                    // 2M
    bf16_t* vc   = kc + XN;                   // 2M
    bf16_t* y    = vc + XN;                   // 2M

    // 1) prep: transpose wq/wk/wv + cast vq/vk/vv
    prep_k<<<dim3(3264), dim3(256), 0, stream>>>(
        (const float*)d_in[1], (const float*)d_in[3], (const float*)d_in[5],
        (const float*)d_in[7], (const float*)d_in[9], (const float*)d_in[11],
        wT, vbf);

    // 2) combine GEMM (64x64, 768 blocks = 3/CU) + independent fillers
    combine_k<<<dim3(4608), dim3(256), 0, stream>>>(
        vbf, wT, Wc,
        (const float*)d_in[0], xbf,
        (const float*)d_in[13], wobf,
        (const float*)d_in[7], (const float*)d_in[9], (const float*)d_in[11],
        (const float*)d_in[2], (const float*)d_in[4], (const float*)d_in[6],
        (const float*)d_in[8], (const float*)d_in[10], (const float*)d_in[12],
        bqc);

    // 3) QKV: q scaled natural; k/v fragment-order (128x128, 384 blocks)
    gemm_k<1, 128, 128, true, 16, 8, 3><<<dim3(384), dim3(256), 0, stream>>>(
        xbf, xbf, xbf, Wc, Wc + WN, Wc + 2 * WN,
        bqc, bqc + 1024, bqc + 2048, q, kc, vc);

    // 4) attention + permuted scatter into y
    attn_k<<<dim3(4, 64, 2), dim3(512), 0, stream>>>(q, kc, vc, y);

    // 5) out = y @ wo^T + b (f32), 64x64 tiles: 512 blocks = 2/CU balanced
    gemm_k<2, 64, 64, true, 32, 16, 1><<<dim3(512), dim3(256), 0, stream>>>(
        y, y, y, wobf, wobf, wobf,
        (const float*)d_in[14], nullptr, nullptr, d_out, d_out, d_out);
}